// Round 5
// baseline (2444.122 us; speedup 1.0000x reference)
//
#include <hip/hip_runtime.h>
#include <hip/hip_bf16.h>
#include <math.h>

// Problem constants (ViT): B=8, C=3, H=384, P=16 -> 24x24=576 patches, S=577
#define BB 8
#define CC 3
#define HH 384
#define PP 16
#define HP 24            // H/P
#define NP 576           // patches per image
#define PD 768           // patch dim = C*P*P
#define DIM 768
#define DEPTH 8
#define HEADS 12
#define DH 64            // DIM/HEADS
#define MLP 3072
#define SS 577           // seq len = NP+1
#define BS (BB*SS)       // 4616 rows
#define MPAD 4736        // 37*128, padded row count for GEMM A-operands
#define LN_EPS 1e-5f
#define NKT 10           // ceil(577/64) key tiles
#define QW (3*DIM)       // qkv row width 2304

typedef __attribute__((ext_vector_type(8))) short s8v;   // 8 bf16 = 4 VGPRs
typedef __attribute__((ext_vector_type(4))) float f4v;   // MFMA accum

__device__ __forceinline__ float bf2f(unsigned short s) {
    union { unsigned u; float f; } x;
    x.u = ((unsigned)s) << 16;
    return x.f;
}
__device__ __forceinline__ unsigned short f2bfu(float f) {
    __hip_bfloat16 h = __float2bfloat16(f);
    return *reinterpret_cast<unsigned short*>(&h);
}

// async global->LDS, 16B per lane; LDS dest = base + lane*16 (wave-uniform base)
__device__ __forceinline__ void async16(void* lds, const void* g) {
    __builtin_amdgcn_global_load_lds(
        (const __attribute__((address_space(1))) void*)(uintptr_t)g,
        (__attribute__((address_space(3))) void*)(unsigned)(uintptr_t)lds,
        16, 0, 0);
}

// ---------------------------------------------------------------------------
// Patchify: img (B,C,H,H) -> Xp_bf (B*NP, PD) bf16, vec index (p1*P+p2)*C + c
// ---------------------------------------------------------------------------
__global__ __launch_bounds__(256) void patchify_k(const float* __restrict__ img,
                                                  unsigned short* __restrict__ xp) {
    int idx = blockIdx.x * 256 + threadIdx.x;
    const int total = BB * NP * PD;
    if (idx >= total) return;
    int b = idx / (NP * PD);
    int r = idx % (NP * PD);
    int n = r / PD;
    int j = r % PD;
    int c  = j % CC;
    int t  = j / CC;
    int p2 = t % PP;
    int p1 = t / PP;
    int hh = n / HP;
    int ww = n % HP;
    int row = hh * PP + p1;
    int col = ww * PP + p2;
    xp[idx] = f2bfu(img[(((size_t)b * CC + c) * HH + row) * HH + col]);
}

// ---------------------------------------------------------------------------
// Weight convert + transpose: W (K,N) fp32 -> Wt (N,K) bf16.  K,N % 32 == 0.
// ---------------------------------------------------------------------------
__global__ __launch_bounds__(256) void convT_k(const float* __restrict__ W,
                                               unsigned short* __restrict__ Wt,
                                               int K, int N) {
    __shared__ float t[32][33];
    int tx = threadIdx.x & 31, ty = threadIdx.x >> 5;   // 32 x 8
    int n0 = blockIdx.x * 32, k0 = blockIdx.y * 32;
#pragma unroll
    for (int i = 0; i < 32; i += 8)
        t[ty + i][tx] = W[(size_t)(k0 + ty + i) * N + n0 + tx];
    __syncthreads();
#pragma unroll
    for (int i = 0; i < 32; i += 8)
        Wt[(size_t)(n0 + ty + i) * K + k0 + tx] = f2bfu(t[tx][ty + i]);
}

// ---------------------------------------------------------------------------
// Fused per-layer weight conversion: all 4 weights of one layer in one launch.
// Tile ranges (32x32 tiles): qkv (768,2304)=1728, out (768,768)=576,
// ff1 (768,3072)=2304, ff2 (3072,768)=2304 -> 6912 blocks total.
// ---------------------------------------------------------------------------
__global__ __launch_bounds__(256) void convT4_k(const float* __restrict__ s0,
                                                const float* __restrict__ s1,
                                                const float* __restrict__ s2,
                                                const float* __restrict__ s3,
                                                unsigned short* __restrict__ d0,
                                                unsigned short* __restrict__ d1,
                                                unsigned short* __restrict__ d2,
                                                unsigned short* __restrict__ d3) {
    __shared__ float t[32][33];
    int bid = blockIdx.x;
    const float* S; unsigned short* D; int K, N, lt;
    if (bid < 1728)      { S = s0; D = d0; K = 768;  N = 2304; lt = bid; }
    else if (bid < 2304) { S = s1; D = d1; K = 768;  N = 768;  lt = bid - 1728; }
    else if (bid < 4608) { S = s2; D = d2; K = 768;  N = 3072; lt = bid - 2304; }
    else                 { S = s3; D = d3; K = 3072; N = 768;  lt = bid - 4608; }
    int ntn = N >> 5;
    int n0 = (lt % ntn) * 32, k0 = (lt / ntn) * 32;
    int tx = threadIdx.x & 31, ty = threadIdx.x >> 5;   // 32 x 8
#pragma unroll
    for (int i = 0; i < 32; i += 8)
        t[ty + i][tx] = S[(size_t)(k0 + ty + i) * N + n0 + tx];
    __syncthreads();
#pragma unroll
    for (int i = 0; i < 32; i += 8)
        D[(size_t)(n0 + ty + i) * K + k0 + tx] = f2bfu(t[tx][ty + i]);
}

// ---------------------------------------------------------------------------
// Build residual stream x (B,S,DIM) fp32
// ---------------------------------------------------------------------------
__global__ __launch_bounds__(256) void build_x_k(const float* __restrict__ pe,
                                                 const float* __restrict__ cls,
                                                 const float* __restrict__ pos,
                                                 float* __restrict__ x) {
    int idx = blockIdx.x * 256 + threadIdx.x;
    const int total = BB * SS * DIM;
    if (idx >= total) return;
    int b = idx / (SS * DIM);
    int r = idx % (SS * DIM);
    int i = r / DIM;
    int d = r % DIM;
    float p = pos[i * DIM + d];
    float v = (i == 0) ? cls[d] : pe[((size_t)b * NP + (i - 1)) * DIM + d];
    x[idx] = v + p;
}

// ---------------------------------------------------------------------------
// LayerNorm (+ optional 2-slice partial-sum residual add): one block per row.
// NPART==0: y = LN(x)            (x untouched)
// NPART==2: xn = x + P0 + P1; store xn to x; y = LN(xn)
// Partial slice stride is BS*DIM floats.
// ---------------------------------------------------------------------------
template <int NPART>
__global__ __launch_bounds__(256) void ln_k(const float* __restrict__ x,
                                            const float* __restrict__ P,
                                            const float* __restrict__ g,
                                            const float* __restrict__ bt,
                                            unsigned short* __restrict__ y,
                                            float* __restrict__ xout) {
    __shared__ float sm[8];
    int row = blockIdx.x, tid = threadIdx.x;
    const float* xr = x + (size_t)row * DIM;
    float v0 = xr[tid], v1 = xr[tid + 256], v2 = xr[tid + 512];
    if (NPART == 2) {
        const float* p0 = P + (size_t)row * DIM;
        const float* p1 = P + (size_t)(BS + row) * DIM;
        v0 += p0[tid]       + p1[tid];
        v1 += p0[tid + 256] + p1[tid + 256];
        v2 += p0[tid + 512] + p1[tid + 512];
        float* xo = xout + (size_t)row * DIM;
        xo[tid] = v0; xo[tid + 256] = v1; xo[tid + 512] = v2;
    }
    float s = v0 + v1 + v2;
    for (int o = 32; o; o >>= 1) s += __shfl_xor(s, o);
    if ((tid & 63) == 0) sm[tid >> 6] = s;
    __syncthreads();
    float mean = (sm[0] + sm[1] + sm[2] + sm[3]) * (1.f / 768.f);
    float q0 = v0 - mean, q1 = v1 - mean, q2 = v2 - mean;
    float s2 = q0 * q0 + q1 * q1 + q2 * q2;
    for (int o = 32; o; o >>= 1) s2 += __shfl_xor(s2, o);
    if ((tid & 63) == 0) sm[4 + (tid >> 6)] = s2;
    __syncthreads();
    float var = (sm[4] + sm[5] + sm[6] + sm[7]) * (1.f / 768.f);
    float rstd = rsqrtf(var + LN_EPS);
    unsigned short* yr = y + (size_t)row * DIM;
    yr[tid]       = f2bfu(q0 * rstd * g[tid]       + bt[tid]);
    yr[tid + 256] = f2bfu(q1 * rstd * g[tid + 256] + bt[tid + 256]);
    yr[tid + 512] = f2bfu(q2 * rstd * g[tid + 512] + bt[tid + 512]);
}

// ---------------------------------------------------------------------------
// bf16 MFMA GEMM v6: LDS-pipe-optimized.
//  - BK=64, subtile = 8 rows x 128B, XOR chunk swizzle (slot = chunk ^ (row&7))
//    applied BOTH sides: inverse-swizzled global source (each row's 8 lanes
//    still cover one 128B line -> coalescing kept) + swizzled ds_read.
//    Kills the 8-way phase conflict of 64B-stride rows.
//  - 8 waves as 2M x 2N x 2K: wave-tile 64x64 (acc[4][4]), K-pair split,
//    merged through LDS at the end. ds_read per FLOP -33% vs 64x32 tiles.
//  - 2-buffer LDS (64KB), counted vmcnt (2-step prefetch lead), raw barriers
//    with explicit lgkmcnt only (loads stay in flight across barriers).
//   A:  (Mpad, K) bf16 row-major; Bt: (N, K) bf16 row-major
//   OP 0: bf16 out = acc + bias      (bias may be null)
//   OP 1: bf16 out = gelu(acc+bias)
//   OP 2: fp32 C += acc + bias
//   OP 3: fp32 out = acc + bias
//   OP 4: fp32 partial store: C[z*M*N + idx] = acc (+bias only on z==0)
// ---------------------------------------------------------------------------
template <int OP, int SPLIT>
__global__ __launch_bounds__(512) void mgemm_k(const unsigned short* __restrict__ A,
                                               const unsigned short* __restrict__ Bt,
                                               const float* __restrict__ bias,
                                               void* __restrict__ Cv,
                                               int M, int N, int K) {
    __shared__ unsigned short Lds[2][2][128 * 64];   // [buf][mat][row*64 + k] = 64 KB
    int tid = threadIdx.x;
    int wv = tid >> 6, lane = tid & 63;
    int quad = lane >> 4, l16 = lane & 15;
    int kp = wv & 1;                 // K-half of the BK=64 step
    int pos = wv >> 1;               // 0..3 output quadrant
    int wm = (pos >> 1) * 64, wn = (pos & 1) * 64;
    int m0 = blockIdx.y * 128, n0 = blockIdx.x * 128;
    int srow = lane >> 3;                       // row in 8-row subtile
    int sk = ((lane & 7) ^ srow) * 8;           // swizzled k-chunk (shorts)

    const int Ks = K / SPLIT;
    const int kbase = blockIdx.z * Ks;
    const int T = Ks / 64;

    f4v acc[4][4];
    const f4v zero = {0.f, 0.f, 0.f, 0.f};
#pragma unroll
    for (int i = 0; i < 4; ++i)
#pragma unroll
        for (int j = 0; j < 4; ++j) acc[i][j] = zero;

    // wave stages subtiles 2wv, 2wv+1 of A and of B (4 async16 per wave)
    auto stage = [&](int t, int bufi) {
#pragma unroll
        for (int s2 = 0; s2 < 2; ++s2) {
            int sub = wv * 2 + s2;              // 0..15
            int row = sub * 8 + srow;           // 0..127
            const unsigned short* ga =
                A + (size_t)(m0 + row) * K + kbase + t * 64 + sk;
            async16(&Lds[bufi][0][sub * 512], ga);
            const unsigned short* gb =
                Bt + (size_t)(n0 + row) * K + kbase + t * 64 + sk;
            async16(&Lds[bufi][1][sub * 512], gb);
        }
    };

    stage(0, 0);
    stage(1, 1);

    const int coff = ((kp * 4 + quad) ^ (l16 & 7)) << 3;   // swizzled read slot

    for (int t = 0; t < T; ++t) {
        int cur = t & 1;
        if (t < T - 1) asm volatile("s_waitcnt vmcnt(4)" ::: "memory");
        else           asm volatile("s_waitcnt vmcnt(0)" ::: "memory");
        __builtin_amdgcn_s_barrier();           // tile t visible to all waves

        s8v af[4], bf[4];
#pragma unroll
        for (int i = 0; i < 4; ++i)
            af[i] = *reinterpret_cast<const s8v*>(
                &Lds[cur][0][(wm + i * 16 + l16) * 64 + coff]);
#pragma unroll
        for (int j = 0; j < 4; ++j)
            bf[j] = *reinterpret_cast<const s8v*>(
                &Lds[cur][1][(wn + j * 16 + l16) * 64 + coff]);
        asm volatile("s_waitcnt lgkmcnt(0)" ::: "memory");
        __builtin_amdgcn_sched_barrier(0);
        __builtin_amdgcn_s_barrier();           // all reads of buf cur done
        if (t + 2 < T) stage(t + 2, cur);       // overwrite cur; lands by t+2

        __builtin_amdgcn_s_setprio(1);
#pragma unroll
        for (int i = 0; i < 4; ++i)
#pragma unroll
            for (int j = 0; j < 4; ++j)
                acc[i][j] = __builtin_amdgcn_mfma_f32_16x16x32_bf16(af[i], bf[j], acc[i][j], 0, 0, 0);
        __builtin_amdgcn_s_setprio(0);
    }

    // K-pair merge through LDS: kp=1 writes, kp=0 adds. Staging is fully
    // drained (vmcnt(0) + barriers in last iter), safe to reuse the buffers.
    __builtin_amdgcn_s_barrier();
    float* mrg = (float*)&Lds[0][0][0];         // 4 pos x 16 KB = 64 KB
    if (kp == 1) {
#pragma unroll
        for (int i = 0; i < 4; ++i)
#pragma unroll
            for (int j = 0; j < 4; ++j)
                *reinterpret_cast<f4v*>(&mrg[pos * 4096 + (i * 4 + j) * 256 + lane * 4]) = acc[i][j];
    }
    asm volatile("s_waitcnt lgkmcnt(0)" ::: "memory");
    __builtin_amdgcn_s_barrier();
    if (kp != 0) return;
#pragma unroll
    for (int i = 0; i < 4; ++i)
#pragma unroll
        for (int j = 0; j < 4; ++j)
            acc[i][j] += *reinterpret_cast<const f4v*>(&mrg[pos * 4096 + (i * 4 + j) * 256 + lane * 4]);

    // epilogue: C/D layout col=lane&15, row=quad*4+reg
#pragma unroll
    for (int j = 0; j < 4; ++j) {
        int col = n0 + wn + j * 16 + l16;
        float bj = bias ? bias[col] : 0.f;
        if (SPLIT > 1 && blockIdx.z != 0) bj = 0.f;
#pragma unroll
        for (int i = 0; i < 4; ++i) {
#pragma unroll
            for (int r = 0; r < 4; ++r) {
                int row = m0 + wm + i * 16 + quad * 4 + r;
                if (row >= M) continue;
                float v = acc[i][j][r] + bj;
                size_t idx = (size_t)row * N + col;
                if (OP == 0) {
                    ((unsigned short*)Cv)[idx] = f2bfu(v);
                } else if (OP == 1) {
                    v = 0.5f * v * (1.f + erff(v * 0.70710678118654752f));
                    ((unsigned short*)Cv)[idx] = f2bfu(v);
                } else if (OP == 2) {
                    float* C = (float*)Cv;
                    if (SPLIT > 1) atomicAdd(&C[idx], v);
                    else C[idx] += v;
                } else if (OP == 3) {
                    ((float*)Cv)[idx] = v;
                } else {
                    float* C = (float*)Cv + (size_t)blockIdx.z * ((size_t)M * N);
                    C[idx] = v;
                }
            }
        }
    }
}

// ---------------------------------------------------------------------------
// MFMA flash attention (bf16, fp32 softmax). One block per (b*h, q-tile 64).
// 4 waves; wave w owns queries q0+w*16..+15. No 1/sqrt(d) scale (faithful).
// ---------------------------------------------------------------------------
__global__ __launch_bounds__(256) void mattn_k(const unsigned short* __restrict__ qkv,
                                               unsigned short* __restrict__ o) {
    __shared__ unsigned short Kl[64 * 72];
    __shared__ unsigned short Vt[64 * 72];
    __shared__ unsigned short Pw[4][16 * 72];

    int tid = threadIdx.x;
    int w = tid >> 6, lane = tid & 63, quad = lane >> 4, l16 = lane & 15;
    int bh = blockIdx.x;
    int b = bh / HEADS, h = bh % HEADS;
    int q0 = blockIdx.y * 64;

    int qq = q0 + w * 16 + l16;
    if (qq > SS - 1) qq = SS - 1;
    const unsigned short* qp = qkv + (size_t)(b * SS + qq) * QW + h * DH + quad * 8;
    s8v aq0 = *reinterpret_cast<const s8v*>(qp);
    s8v aq1 = *reinterpret_cast<const s8v*>(qp + 32);

    float m[4], l[4];
    f4v O[4];
    const f4v zero = {0.f, 0.f, 0.f, 0.f};
#pragma unroll
    for (int r = 0; r < 4; ++r) { m[r] = -INFINITY; l[r] = 0.f; }
#pragma unroll
    for (int dg = 0; dg < 4; ++dg) O[dg] = zero;

    for (int t = 0; t < NKT; ++t) {
        int k0 = t * 64;
        __syncthreads();
#pragma unroll
        for (int rr = 0; rr < 2; ++rr) {
            int cid = tid + rr * 256;
            int row = cid >> 3, cb = (cid & 7) * 8;
            s8v kv = *reinterpret_cast<const s8v*>(
                qkv + (size_t)(b * SS + k0 + row) * QW + DIM + h * DH + cb);
            *reinterpret_cast<s8v*>(&Kl[row * 72 + cb]) = kv;
        }
        {
            int kb = (tid & 15) * 4, db = (tid >> 4) * 4;
            const unsigned short* vb = qkv + (size_t)(b * SS + k0 + kb) * QW + 2 * DIM + h * DH + db;
            ushort4 r0 = *reinterpret_cast<const ushort4*>(vb);
            ushort4 r1 = *reinterpret_cast<const ushort4*>(vb + QW);
            ushort4 r2 = *reinterpret_cast<const ushort4*>(vb + 2 * QW);
            ushort4 r3 = *reinterpret_cast<const ushort4*>(vb + 3 * QW);
            ushort4 w0 = {r0.x, r1.x, r2.x, r3.x};
            ushort4 w1 = {r0.y, r1.y, r2.y, r3.y};
            ushort4 w2 = {r0.z, r1.z, r2.z, r3.z};
            ushort4 w3 = {r0.w, r1.w, r2.w, r3.w};
            *reinterpret_cast<ushort4*>(&Vt[(db + 0) * 72 + kb]) = w0;
            *reinterpret_cast<ushort4*>(&Vt[(db + 1) * 72 + kb]) = w1;
            *reinterpret_cast<ushort4*>(&Vt[(db + 2) * 72 + kb]) = w2;
            *reinterpret_cast<ushort4*>(&Vt[(db + 3) * 72 + kb]) = w3;
        }
        __syncthreads();

        f4v s[4];
#pragma unroll
        for (int kk = 0; kk < 4; ++kk) {
            const unsigned short* kp = &Kl[(kk * 16 + l16) * 72 + quad * 8];
            s8v b0 = *reinterpret_cast<const s8v*>(kp);
            s8v b1 = *reinterpret_cast<const s8v*>(kp + 32);
            f4v z = zero;
            z = __builtin_amdgcn_mfma_f32_16x16x32_bf16(aq0, b0, z, 0, 0, 0);
            z = __builtin_amdgcn_mfma_f32_16x16x32_bf16(aq1, b1, z, 0, 0, 0);
            s[kk] = z;
        }
        int kvalid = SS - k0;
        if (kvalid < 64) {
#pragma unroll
            for (int kk = 0; kk < 4; ++kk)
                if (kk * 16 + l16 >= kvalid) {
                    f4v mk = {-1e30f, -1e30f, -1e30f, -1e30f};
                    s[kk] = mk;
                }
        }
        float alpha[4];
#pragma unroll
        for (int r = 0; r < 4; ++r) {
            float mx = fmaxf(fmaxf(s[0][r], s[1][r]), fmaxf(s[2][r], s[3][r]));
#pragma unroll
            for (int off = 1; off < 16; off <<= 1) mx = fmaxf(mx, __shfl_xor(mx, off));
            float mn = fmaxf(m[r], mx);
            alpha[r] = __expf(m[r] - mn);
            m[r] = mn;
            float ps = 0.f;
#pragma unroll
            for (int kk = 0; kk < 4; ++kk) {
                float p = __expf(s[kk][r] - mn);
                ps += p;
                Pw[w][(quad * 4 + r) * 72 + kk * 16 + l16] = f2bfu(p);
            }
#pragma unroll
            for (int off = 1; off < 16; off <<= 1) ps += __shfl_xor(ps, off);
            l[r] = l[r] * alpha[r] + ps;
        }
#pragma unroll
        for (int dg = 0; dg < 4; ++dg)
#pragma unroll
            for (int r = 0; r < 4; ++r) O[dg][r] *= alpha[r];

        s8v ap0 = *reinterpret_cast<const s8v*>(&Pw[w][l16 * 72 + quad * 8]);
        s8v ap1 = *reinterpret_cast<const s8v*>(&Pw[w][l16 * 72 + 32 + quad * 8]);
#pragma unroll
        for (int dg = 0; dg < 4; ++dg) {
            const unsigned short* vp = &Vt[(dg * 16 + l16) * 72 + quad * 8];
            s8v bv0 = *reinterpret_cast<const s8v*>(vp);
            s8v bv1 = *reinterpret_cast<const s8v*>(vp + 32);
            O[dg] = __builtin_amdgcn_mfma_f32_16x16x32_bf16(ap0, bv0, O[dg], 0, 0, 0);
            O[dg] = __builtin_amdgcn_mfma_f32_16x16x32_bf16(ap1, bv1, O[dg], 0, 0, 0);
        }
    }

#pragma unroll
    for (int r = 0; r < 4; ++r) {
        int q = q0 + w * 16 + quad * 4 + r;
        if (q >= SS) continue;
        float inv = 1.f / l[r];
        unsigned short* op = o + (size_t)(b * SS + q) * DIM + h * DH + l16;
#pragma unroll
        for (int dg = 0; dg < 4; ++dg)
            op[dg * 16] = f2bfu(O[dg][r] * inv);
    }
}

// ---------------------------------------------------------------------------
// Output: x[:, 1:, :] (+ optional 2 partial slices) fp32 -> out (B, NP, DIM)
// ---------------------------------------------------------------------------
template <int NPART>
__global__ __launch_bounds__(256) void copy_out_k(const float* __restrict__ x,
                                                  const float* __restrict__ P,
                                                  float* __restrict__ out) {
    int idx = blockIdx.x * 256 + threadIdx.x;
    const int total = BB * NP * DIM;
    if (idx >= total) return;
    int b = idx / (NP * DIM);
    int r = idx % (NP * DIM);
    int n = r / DIM;
    int d = r % DIM;
    size_t row = (size_t)b * SS + 1 + n;
    float v = x[row * DIM + d];
    if (NPART == 2)
        v += P[row * DIM + d] + P[(size_t)BS * DIM + row * DIM + d];
    out[idx] = v;
}

// ---------------------------------------------------------------------------
extern "C" void kernel_launch(void* const* d_in, const int* in_sizes, int n_in,
                              void* d_out, int out_size, void* d_ws, size_t ws_size,
                              hipStream_t stream) {
    const float* img     = (const float*)d_in[0];
    const float* pos     = (const float*)d_in[1];
    const float* cls     = (const float*)d_in[2];
    const float* patch_w = (const float*)d_in[3];
    const float* patch_b = (const float*)d_in[4];
    const float* ln1_g   = (const float*)d_in[5];
    const float* ln1_b   = (const float*)d_in[6];
    const float* qkv_w   = (const float*)d_in[7];
    const float* out_w   = (const float*)d_in[8];
    const float* out_b   = (const float*)d_in[9];
    const float* ln2_g   = (const float*)d_in[10];
    const float* ln2_b   = (const float*)d_in[11];
    const float* ff1_w   = (const float*)d_in[12];
    const float* ff1_b   = (const float*)d_in[13];
    const float* ff2_w   = (const float*)d_in[14];
    const float* ff2_b   = (const float*)d_in[15];
    float* out = (float*)d_out;

    // workspace layout
    char* base = (char*)d_ws;
    float* x = (float*)base;                          base += (size_t)BS * DIM * 4;
    unsigned short* y_bf   = (unsigned short*)base;   base += (size_t)MPAD * DIM * 2;
    unsigned short* t1_bf  = (unsigned short*)base;   base += (size_t)MPAD * DIM * 2;
    unsigned short* qkv_bf = (unsigned short*)base;   base += (size_t)MPAD * 3 * DIM * 2;
    unsigned short* hid_bf = (unsigned short*)base;   base += (size_t)MPAD * MLP * 2;
    unsigned short* xp_bf  = (unsigned short*)base;   base += (size_t)BB * NP * PD * 2;
    // per-layer transposed bf16 weights
    unsigned short* wq_t = (unsigned short*)base;     base += (size_t)(3 * DIM) * DIM * 2;
    unsigned short* wo_t = (unsigned short*)base;     base += (size_t)DIM * DIM * 2;
    unsigned short* w1_t = (unsigned short*)base;     base += (size_t)MLP * DIM * 2;
    unsigned short* w2_t = (unsigned short*)base;     base += (size_t)DIM * MLP * 2;
    // 2-slice fp32 split-K partial buffer
    float* part = (float*)base;                       base += (size_t)2 * BS * DIM * 4;
    float* pe_f32 = (float*)hid_bf;   // patch-embed fp32 out, alias (consumed pre-loop)

    const int threads = 256;
    const int gthreads = 512;            // 8-wave GEMM blocks
    const int mblk = (BS + 127) / 128;   // 37

    patchify_k<<<(BB * NP * PD + 255) / 256, threads, 0, stream>>>(img, xp_bf);
    convT_k<<<dim3(DIM / 32, PD / 32), threads, 0, stream>>>(patch_w, wq_t, PD, DIM);
    mgemm_k<3, 1><<<dim3(DIM / 128, (BB * NP) / 128), gthreads, 0, stream>>>(
        xp_bf, wq_t, patch_b, pe_f32, BB * NP, DIM, PD);
    build_x_k<<<(BB * SS * DIM + 255) / 256, threads, 0, stream>>>(pe_f32, cls, pos, x);

    for (int l = 0; l < DEPTH; ++l) {
        // ln1: layer 0 plain; later layers fold in previous ff2 partials
        if (l == 0)
            ln_k<0><<<BS, threads, 0, stream>>>(x, nullptr, ln1_g, ln1_b, y_bf, nullptr);
        else
            ln_k<2><<<BS, threads, 0, stream>>>(x, part, ln1_g + l * DIM, ln1_b + l * DIM,
                                                y_bf, x);
        // all 4 weight conversions for this layer, one launch
        convT4_k<<<6912, threads, 0, stream>>>(
            qkv_w + (size_t)l * DIM * 3 * DIM,
            out_w + (size_t)l * DIM * DIM,
            ff1_w + (size_t)l * DIM * MLP,
            ff2_w + (size_t)l * MLP * DIM,
            wq_t, wo_t, w1_t, w2_t);
        mgemm_k<0, 1><<<dim3(3 * DIM / 128, mblk), gthreads, 0, stream>>>(
            y_bf, wq_t, nullptr, qkv_bf, BS, 3 * DIM, DIM);
        // MFMA flash attention -> t1
        mattn_k<<<dim3(BB * HEADS, NKT), threads, 0, stream>>>(qkv_bf, t1_bf);
        // attn-out: split-K x2 partial stores (no atomics); reduced inside ln2
        mgemm_k<4, 2><<<dim3(DIM / 128, mblk, 2), gthreads, 0, stream>>>(
            t1_bf, wo_t, out_b + l * DIM, part, BS, DIM, DIM);
        // ln2: x += attn partials, then LN
        ln_k<2><<<BS, threads, 0, stream>>>(x, part, ln2_g + l * DIM, ln2_b + l * DIM,
                                            y_bf, x);
        mgemm_k<1, 1><<<dim3(MLP / 128, mblk), gthreads, 0, stream>>>(
            y_bf, w1_t, ff1_b + l * MLP, hid_bf, BS, MLP, DIM);
        // ff2: split-K x2 partial stores; reduced inside next ln1 (or copy_out)
        mgemm_k<4, 2><<<dim3(DIM / 128, mblk, 2), gthreads, 0, stream>>>(
            hid_bf, w2_t, ff2_b + l * DIM, part, BS, DIM, MLP);
    }

    copy_out_k<2><<<(BB * NP * DIM + 255) / 256, threads, 0, stream>>>(x, part, out);
}

// Round 6
// 1955.205 us; speedup vs baseline: 1.2501x; 1.2501x over previous
//
#include <hip/hip_runtime.h>
#include <hip/hip_bf16.h>
#include <math.h>

// Problem constants (ViT): B=8, C=3, H=384, P=16 -> 24x24=576 patches, S=577
#define BB 8
#define CC 3
#define HH 384
#define PP 16
#define HP 24            // H/P
#define NP 576           // patches per image
#define PD 768           // patch dim = C*P*P
#define DIM 768
#define DEPTH 8
#define HEADS 12
#define DH 64            // DIM/HEADS
#define MLP 3072
#define SS 577           // seq len = NP+1
#define BS (BB*SS)       // 4616 rows
#define MPAD 4736        // 37*128, padded row count for GEMM A-operands
#define LN_EPS 1e-5f
#define NKT 10           // ceil(577/64) key tiles
#define QW (3*DIM)       // qkv row width 2304

typedef __attribute__((ext_vector_type(8))) short s8v;   // 8 bf16 = 4 VGPRs
typedef __attribute__((ext_vector_type(4))) float f4v;   // MFMA accum

__device__ __forceinline__ float bf2f(unsigned short s) {
    union { unsigned u; float f; } x;
    x.u = ((unsigned)s) << 16;
    return x.f;
}
__device__ __forceinline__ unsigned short f2bfu(float f) {
    __hip_bfloat16 h = __float2bfloat16(f);
    return *reinterpret_cast<unsigned short*>(&h);
}

// async global->LDS, 16B per lane; LDS dest = base + lane*16 (wave-uniform base)
__device__ __forceinline__ void async16(void* lds, const void* g) {
    __builtin_amdgcn_global_load_lds(
        (const __attribute__((address_space(1))) void*)(uintptr_t)g,
        (__attribute__((address_space(3))) void*)(unsigned)(uintptr_t)lds,
        16, 0, 0);
}

// ---------------------------------------------------------------------------
// Patchify: img (B,C,H,H) -> Xp_bf (B*NP, PD) bf16, vec index (p1*P+p2)*C + c
// ---------------------------------------------------------------------------
__global__ __launch_bounds__(256) void patchify_k(const float* __restrict__ img,
                                                  unsigned short* __restrict__ xp) {
    int idx = blockIdx.x * 256 + threadIdx.x;
    const int total = BB * NP * PD;
    if (idx >= total) return;
    int b = idx / (NP * PD);
    int r = idx % (NP * PD);
    int n = r / PD;
    int j = r % PD;
    int c  = j % CC;
    int t  = j / CC;
    int p2 = t % PP;
    int p1 = t / PP;
    int hh = n / HP;
    int ww = n % HP;
    int row = hh * PP + p1;
    int col = ww * PP + p2;
    xp[idx] = f2bfu(img[(((size_t)b * CC + c) * HH + row) * HH + col]);
}

// ---------------------------------------------------------------------------
// Weight convert + transpose: W (K,N) fp32 -> Wt (N,K) bf16.  K,N % 32 == 0.
// ---------------------------------------------------------------------------
__global__ __launch_bounds__(256) void convT_k(const float* __restrict__ W,
                                               unsigned short* __restrict__ Wt,
                                               int K, int N) {
    __shared__ float t[32][33];
    int tx = threadIdx.x & 31, ty = threadIdx.x >> 5;   // 32 x 8
    int n0 = blockIdx.x * 32, k0 = blockIdx.y * 32;
#pragma unroll
    for (int i = 0; i < 32; i += 8)
        t[ty + i][tx] = W[(size_t)(k0 + ty + i) * N + n0 + tx];
    __syncthreads();
#pragma unroll
    for (int i = 0; i < 32; i += 8)
        Wt[(size_t)(n0 + ty + i) * K + k0 + tx] = f2bfu(t[tx][ty + i]);
}

// ---------------------------------------------------------------------------
// Fused per-layer weight conversion: all 4 weights of one layer in one launch.
// Tile ranges (32x32 tiles): qkv (768,2304)=1728, out (768,768)=576,
// ff1 (768,3072)=2304, ff2 (3072,768)=2304 -> 6912 blocks total.
// ---------------------------------------------------------------------------
__global__ __launch_bounds__(256) void convT4_k(const float* __restrict__ s0,
                                                const float* __restrict__ s1,
                                                const float* __restrict__ s2,
                                                const float* __restrict__ s3,
                                                unsigned short* __restrict__ d0,
                                                unsigned short* __restrict__ d1,
                                                unsigned short* __restrict__ d2,
                                                unsigned short* __restrict__ d3) {
    __shared__ float t[32][33];
    int bid = blockIdx.x;
    const float* S; unsigned short* D; int K, N, lt;
    if (bid < 1728)      { S = s0; D = d0; K = 768;  N = 2304; lt = bid; }
    else if (bid < 2304) { S = s1; D = d1; K = 768;  N = 768;  lt = bid - 1728; }
    else if (bid < 4608) { S = s2; D = d2; K = 768;  N = 3072; lt = bid - 2304; }
    else                 { S = s3; D = d3; K = 3072; N = 768;  lt = bid - 4608; }
    int ntn = N >> 5;
    int n0 = (lt % ntn) * 32, k0 = (lt / ntn) * 32;
    int tx = threadIdx.x & 31, ty = threadIdx.x >> 5;   // 32 x 8
#pragma unroll
    for (int i = 0; i < 32; i += 8)
        t[ty + i][tx] = S[(size_t)(k0 + ty + i) * N + n0 + tx];
    __syncthreads();
#pragma unroll
    for (int i = 0; i < 32; i += 8)
        D[(size_t)(n0 + ty + i) * K + k0 + tx] = f2bfu(t[tx][ty + i]);
}

// ---------------------------------------------------------------------------
// Build residual stream x (B,S,DIM) fp32
// ---------------------------------------------------------------------------
__global__ __launch_bounds__(256) void build_x_k(const float* __restrict__ pe,
                                                 const float* __restrict__ cls,
                                                 const float* __restrict__ pos,
                                                 float* __restrict__ x) {
    int idx = blockIdx.x * 256 + threadIdx.x;
    const int total = BB * SS * DIM;
    if (idx >= total) return;
    int b = idx / (SS * DIM);
    int r = idx % (SS * DIM);
    int i = r / DIM;
    int d = r % DIM;
    float p = pos[i * DIM + d];
    float v = (i == 0) ? cls[d] : pe[((size_t)b * NP + (i - 1)) * DIM + d];
    x[idx] = v + p;
}

// ---------------------------------------------------------------------------
// LayerNorm (+ optional 2-slice partial-sum residual add): one block per row.
// NPART==0: y = LN(x)            (x untouched)
// NPART==2: xn = x + P0 + P1; store xn to x; y = LN(xn)
// Partial slice stride is BS*DIM floats.
// ---------------------------------------------------------------------------
template <int NPART>
__global__ __launch_bounds__(256) void ln_k(const float* __restrict__ x,
                                            const float* __restrict__ P,
                                            const float* __restrict__ g,
                                            const float* __restrict__ bt,
                                            unsigned short* __restrict__ y,
                                            float* __restrict__ xout) {
    __shared__ float sm[8];
    int row = blockIdx.x, tid = threadIdx.x;
    const float* xr = x + (size_t)row * DIM;
    float v0 = xr[tid], v1 = xr[tid + 256], v2 = xr[tid + 512];
    if (NPART == 2) {
        const float* p0 = P + (size_t)row * DIM;
        const float* p1 = P + (size_t)(BS + row) * DIM;
        v0 += p0[tid]       + p1[tid];
        v1 += p0[tid + 256] + p1[tid + 256];
        v2 += p0[tid + 512] + p1[tid + 512];
        float* xo = xout + (size_t)row * DIM;
        xo[tid] = v0; xo[tid + 256] = v1; xo[tid + 512] = v2;
    }
    float s = v0 + v1 + v2;
    for (int o = 32; o; o >>= 1) s += __shfl_xor(s, o);
    if ((tid & 63) == 0) sm[tid >> 6] = s;
    __syncthreads();
    float mean = (sm[0] + sm[1] + sm[2] + sm[3]) * (1.f / 768.f);
    float q0 = v0 - mean, q1 = v1 - mean, q2 = v2 - mean;
    float s2 = q0 * q0 + q1 * q1 + q2 * q2;
    for (int o = 32; o; o >>= 1) s2 += __shfl_xor(s2, o);
    if ((tid & 63) == 0) sm[4 + (tid >> 6)] = s2;
    __syncthreads();
    float var = (sm[4] + sm[5] + sm[6] + sm[7]) * (1.f / 768.f);
    float rstd = rsqrtf(var + LN_EPS);
    unsigned short* yr = y + (size_t)row * DIM;
    yr[tid]       = f2bfu(q0 * rstd * g[tid]       + bt[tid]);
    yr[tid + 256] = f2bfu(q1 * rstd * g[tid + 256] + bt[tid + 256]);
    yr[tid + 512] = f2bfu(q2 * rstd * g[tid + 512] + bt[tid + 512]);
}

// ---------------------------------------------------------------------------
// bf16 MFMA GEMM v7: fat steps for the latency floor.
//  - BK=64: each step = 16 ds_read_b128 + 32 MFMA + 8 DMA per wave, with ONE
//    barrier + ONE vmcnt(0) per step. The drain is issued a full step (~2000
//    cyc) after the loads -> costs ~0, unlike a same-step drain. Steps halve
//    vs BK=32; the fixed per-step rendezvous latency is paid half as often.
//  - 4 waves (256 thr), 2x2 wave grid, 64x64 wave tile, acc[4][4] (R1's
//    proven layout: best MFMA:ds_read ratio, 32:16 per step).
//  - R5's verified both-sides XOR swizzle (source chunk (lane&7)^srow,
//    read slot (kc*4+quad)^(l16&7)): conflict-free ds_read_b128, coalescing
//    kept (each 8-lane group still covers one 128B line).
//  - 2-buffer LDS (64KB): stage(t+1) goes into buf cur^1, whose readers
//    (iter t-1) all passed this iter's barrier after consuming their reads.
//   A:  (Mpad, K) bf16 row-major; Bt: (N, K) bf16 row-major
//   OP 0: bf16 out = acc + bias      (bias may be null)
//   OP 1: bf16 out = gelu(acc+bias)
//   OP 2: fp32 C += acc + bias
//   OP 3: fp32 out = acc + bias
//   OP 4: fp32 partial store: C[z*M*N + idx] = acc (+bias only on z==0)
// ---------------------------------------------------------------------------
template <int OP, int SPLIT>
__global__ __launch_bounds__(256) void mgemm_k(const unsigned short* __restrict__ A,
                                               const unsigned short* __restrict__ Bt,
                                               const float* __restrict__ bias,
                                               void* __restrict__ Cv,
                                               int M, int N, int K) {
    __shared__ unsigned short Al[2][128 * 64];   // 32 KB
    __shared__ unsigned short Bl[2][128 * 64];   // 32 KB
    int tid = threadIdx.x;
    int wv = tid >> 6, lane = tid & 63;
    int quad = lane >> 4, l16 = lane & 15;
    int m0 = blockIdx.y * 128, n0 = blockIdx.x * 128;
    int wm = (wv >> 1) * 64, wn = (wv & 1) * 64;
    int srow = lane >> 3;                 // row within 8-row subtile
    int schunk = ((lane & 7) ^ srow) * 8; // swizzled source k-chunk (shorts)

    const int Ks = K / SPLIT;
    const int kbase = blockIdx.z * Ks;
    const int T = Ks / 64;

    f4v acc[4][4];
    const f4v zero = {0.f, 0.f, 0.f, 0.f};
#pragma unroll
    for (int i = 0; i < 4; ++i)
#pragma unroll
        for (int j = 0; j < 4; ++j) acc[i][j] = zero;

    // wave wv stages subtiles wv*4..wv*4+3 of A and B (8 async16 per wave).
    // Lane l of subtile `sub`: global row sub*8 + (l>>3), chunk (l&7)^srow;
    // DMA writes LDS linearly at sub*1024B + l*16B == row-major slot.
    auto stage = [&](int t, int bufi) {
#pragma unroll
        for (int s = 0; s < 4; ++s) {
            int sub = wv * 4 + s;             // 0..15
            int row = sub * 8 + srow;         // 0..127
            const unsigned short* ga =
                A + (size_t)(m0 + row) * K + kbase + t * 64 + schunk;
            async16(&Al[bufi][sub * 512], ga);
            const unsigned short* gb =
                Bt + (size_t)(n0 + row) * K + kbase + t * 64 + schunk;
            async16(&Bl[bufi][sub * 512], gb);
        }
    };

    stage(0, 0);

    for (int t = 0; t < T; ++t) {
        int cur = t & 1;
        asm volatile("s_waitcnt vmcnt(0)" ::: "memory");   // tile t landed (issued 1 step ago)
        __builtin_amdgcn_s_barrier();
        asm volatile("" ::: "memory");
        if (t + 1 < T) stage(t + 1, cur ^ 1);

        s8v af[2][4], bf[2][4];
#pragma unroll
        for (int kc = 0; kc < 2; ++kc) {
            int slot = ((kc * 4 + quad) ^ (l16 & 7)) * 8;  // swizzled read slot
#pragma unroll
            for (int i = 0; i < 4; ++i)
                af[kc][i] = *reinterpret_cast<const s8v*>(
                    &Al[cur][(wm + i * 16 + l16) * 64 + slot]);
#pragma unroll
            for (int j = 0; j < 4; ++j)
                bf[kc][j] = *reinterpret_cast<const s8v*>(
                    &Bl[cur][(wn + j * 16 + l16) * 64 + slot]);
        }
        __builtin_amdgcn_s_setprio(1);
#pragma unroll
        for (int i = 0; i < 4; ++i)
#pragma unroll
            for (int j = 0; j < 4; ++j) {
                acc[i][j] = __builtin_amdgcn_mfma_f32_16x16x32_bf16(af[0][i], bf[0][j], acc[i][j], 0, 0, 0);
                acc[i][j] = __builtin_amdgcn_mfma_f32_16x16x32_bf16(af[1][i], bf[1][j], acc[i][j], 0, 0, 0);
            }
        __builtin_amdgcn_s_setprio(0);
    }

    // epilogue: C/D layout col=lane&15, row=quad*4+reg
#pragma unroll
    for (int j = 0; j < 4; ++j) {
        int col = n0 + wn + j * 16 + l16;
        float bj = bias ? bias[col] : 0.f;
        if (SPLIT > 1 && blockIdx.z != 0) bj = 0.f;
#pragma unroll
        for (int i = 0; i < 4; ++i) {
#pragma unroll
            for (int r = 0; r < 4; ++r) {
                int row = m0 + wm + i * 16 + quad * 4 + r;
                if (row >= M) continue;
                float v = acc[i][j][r] + bj;
                size_t idx = (size_t)row * N + col;
                if (OP == 0) {
                    ((unsigned short*)Cv)[idx] = f2bfu(v);
                } else if (OP == 1) {
                    v = 0.5f * v * (1.f + erff(v * 0.70710678118654752f));
                    ((unsigned short*)Cv)[idx] = f2bfu(v);
                } else if (OP == 2) {
                    float* C = (float*)Cv;
                    if (SPLIT > 1) atomicAdd(&C[idx], v);
                    else C[idx] += v;
                } else if (OP == 3) {
                    ((float*)Cv)[idx] = v;
                } else {
                    float* C = (float*)Cv + (size_t)blockIdx.z * ((size_t)M * N);
                    C[idx] = v;
                }
            }
        }
    }
}

// ---------------------------------------------------------------------------
// MFMA flash attention (bf16, fp32 softmax). One block per (b*h, q-tile 64).
// 4 waves; wave w owns queries q0+w*16..+15. No 1/sqrt(d) scale (faithful).
// ---------------------------------------------------------------------------
__global__ __launch_bounds__(256) void mattn_k(const unsigned short* __restrict__ qkv,
                                               unsigned short* __restrict__ o) {
    __shared__ unsigned short Kl[64 * 72];
    __shared__ unsigned short Vt[64 * 72];
    __shared__ unsigned short Pw[4][16 * 72];

    int tid = threadIdx.x;
    int w = tid >> 6, lane = tid & 63, quad = lane >> 4, l16 = lane & 15;
    int bh = blockIdx.x;
    int b = bh / HEADS, h = bh % HEADS;
    int q0 = blockIdx.y * 64;

    int qq = q0 + w * 16 + l16;
    if (qq > SS - 1) qq = SS - 1;
    const unsigned short* qp = qkv + (size_t)(b * SS + qq) * QW + h * DH + quad * 8;
    s8v aq0 = *reinterpret_cast<const s8v*>(qp);
    s8v aq1 = *reinterpret_cast<const s8v*>(qp + 32);

    float m[4], l[4];
    f4v O[4];
    const f4v zero = {0.f, 0.f, 0.f, 0.f};
#pragma unroll
    for (int r = 0; r < 4; ++r) { m[r] = -INFINITY; l[r] = 0.f; }
#pragma unroll
    for (int dg = 0; dg < 4; ++dg) O[dg] = zero;

    for (int t = 0; t < NKT; ++t) {
        int k0 = t * 64;
        __syncthreads();
#pragma unroll
        for (int rr = 0; rr < 2; ++rr) {
            int cid = tid + rr * 256;
            int row = cid >> 3, cb = (cid & 7) * 8;
            s8v kv = *reinterpret_cast<const s8v*>(
                qkv + (size_t)(b * SS + k0 + row) * QW + DIM + h * DH + cb);
            *reinterpret_cast<s8v*>(&Kl[row * 72 + cb]) = kv;
        }
        {
            int kb = (tid & 15) * 4, db = (tid >> 4) * 4;
            const unsigned short* vb = qkv + (size_t)(b * SS + k0 + kb) * QW + 2 * DIM + h * DH + db;
            ushort4 r0 = *reinterpret_cast<const ushort4*>(vb);
            ushort4 r1 = *reinterpret_cast<const ushort4*>(vb + QW);
            ushort4 r2 = *reinterpret_cast<const ushort4*>(vb + 2 * QW);
            ushort4 r3 = *reinterpret_cast<const ushort4*>(vb + 3 * QW);
            ushort4 w0 = {r0.x, r1.x, r2.x, r3.x};
            ushort4 w1 = {r0.y, r1.y, r2.y, r3.y};
            ushort4 w2 = {r0.z, r1.z, r2.z, r3.z};
            ushort4 w3 = {r0.w, r1.w, r2.w, r3.w};
            *reinterpret_cast<ushort4*>(&Vt[(db + 0) * 72 + kb]) = w0;
            *reinterpret_cast<ushort4*>(&Vt[(db + 1) * 72 + kb]) = w1;
            *reinterpret_cast<ushort4*>(&Vt[(db + 2) * 72 + kb]) = w2;
            *reinterpret_cast<ushort4*>(&Vt[(db + 3) * 72 + kb]) = w3;
        }
        __syncthreads();

        f4v s[4];
#pragma unroll
        for (int kk = 0; kk < 4; ++kk) {
            const unsigned short* kp = &Kl[(kk * 16 + l16) * 72 + quad * 8];
            s8v b0 = *reinterpret_cast<const s8v*>(kp);
            s8v b1 = *reinterpret_cast<const s8v*>(kp + 32);
            f4v z = zero;
            z = __builtin_amdgcn_mfma_f32_16x16x32_bf16(aq0, b0, z, 0, 0, 0);
            z = __builtin_amdgcn_mfma_f32_16x16x32_bf16(aq1, b1, z, 0, 0, 0);
            s[kk] = z;
        }
        int kvalid = SS - k0;
        if (kvalid < 64) {
#pragma unroll
            for (int kk = 0; kk < 4; ++kk)
                if (kk * 16 + l16 >= kvalid) {
                    f4v mk = {-1e30f, -1e30f, -1e30f, -1e30f};
                    s[kk] = mk;
                }
        }
        float alpha[4];
#pragma unroll
        for (int r = 0; r < 4; ++r) {
            float mx = fmaxf(fmaxf(s[0][r], s[1][r]), fmaxf(s[2][r], s[3][r]));
#pragma unroll
            for (int off = 1; off < 16; off <<= 1) mx = fmaxf(mx, __shfl_xor(mx, off));
            float mn = fmaxf(m[r], mx);
            alpha[r] = __expf(m[r] - mn);
            m[r] = mn;
            float ps = 0.f;
#pragma unroll
            for (int kk = 0; kk < 4; ++kk) {
                float p = __expf(s[kk][r] - mn);
                ps += p;
                Pw[w][(quad * 4 + r) * 72 + kk * 16 + l16] = f2bfu(p);
            }
#pragma unroll
            for (int off = 1; off < 16; off <<= 1) ps += __shfl_xor(ps, off);
            l[r] = l[r] * alpha[r] + ps;
        }
#pragma unroll
        for (int dg = 0; dg < 4; ++dg)
#pragma unroll
            for (int r = 0; r < 4; ++r) O[dg][r] *= alpha[r];

        s8v ap0 = *reinterpret_cast<const s8v*>(&Pw[w][l16 * 72 + quad * 8]);
        s8v ap1 = *reinterpret_cast<const s8v*>(&Pw[w][l16 * 72 + 32 + quad * 8]);
#pragma unroll
        for (int dg = 0; dg < 4; ++dg) {
            const unsigned short* vp = &Vt[(dg * 16 + l16) * 72 + quad * 8];
            s8v bv0 = *reinterpret_cast<const s8v*>(vp);
            s8v bv1 = *reinterpret_cast<const s8v*>(vp + 32);
            O[dg] = __builtin_amdgcn_mfma_f32_16x16x32_bf16(ap0, bv0, O[dg], 0, 0, 0);
            O[dg] = __builtin_amdgcn_mfma_f32_16x16x32_bf16(ap1, bv1, O[dg], 0, 0, 0);
        }
    }

#pragma unroll
    for (int r = 0; r < 4; ++r) {
        int q = q0 + w * 16 + quad * 4 + r;
        if (q >= SS) continue;
        float inv = 1.f / l[r];
        unsigned short* op = o + (size_t)(b * SS + q) * DIM + h * DH + l16;
#pragma unroll
        for (int dg = 0; dg < 4; ++dg)
            op[dg * 16] = f2bfu(O[dg][r] * inv);
    }
}

// ---------------------------------------------------------------------------
// Output: x[:, 1:, :] (+ optional 2 partial slices) fp32 -> out (B, NP, DIM)
// ---------------------------------------------------------------------------
template <int NPART>
__global__ __launch_bounds__(256) void copy_out_k(const float* __restrict__ x,
                                                  const float* __restrict__ P,
                                                  float* __restrict__ out) {
    int idx = blockIdx.x * 256 + threadIdx.x;
    const int total = BB * NP * DIM;
    if (idx >= total) return;
    int b = idx / (NP * DIM);
    int r = idx % (NP * DIM);
    int n = r / DIM;
    int d = r % DIM;
    size_t row = (size_t)b * SS + 1 + n;
    float v = x[row * DIM + d];
    if (NPART == 2)
        v += P[row * DIM + d] + P[(size_t)BS * DIM + row * DIM + d];
    out[idx] = v;
}

// ---------------------------------------------------------------------------
extern "C" void kernel_launch(void* const* d_in, const int* in_sizes, int n_in,
                              void* d_out, int out_size, void* d_ws, size_t ws_size,
                              hipStream_t stream) {
    const float* img     = (const float*)d_in[0];
    const float* pos     = (const float*)d_in[1];
    const float* cls     = (const float*)d_in[2];
    const float* patch_w = (const float*)d_in[3];
    const float* patch_b = (const float*)d_in[4];
    const float* ln1_g   = (const float*)d_in[5];
    const float* ln1_b   = (const float*)d_in[6];
    const float* qkv_w   = (const float*)d_in[7];
    const float* out_w   = (const float*)d_in[8];
    const float* out_b   = (const float*)d_in[9];
    const float* ln2_g   = (const float*)d_in[10];
    const float* ln2_b   = (const float*)d_in[11];
    const float* ff1_w   = (const float*)d_in[12];
    const float* ff1_b   = (const float*)d_in[13];
    const float* ff2_w   = (const float*)d_in[14];
    const float* ff2_b   = (const float*)d_in[15];
    float* out = (float*)d_out;

    // workspace layout
    char* base = (char*)d_ws;
    float* x = (float*)base;                          base += (size_t)BS * DIM * 4;
    unsigned short* y_bf   = (unsigned short*)base;   base += (size_t)MPAD * DIM * 2;
    unsigned short* t1_bf  = (unsigned short*)base;   base += (size_t)MPAD * DIM * 2;
    unsigned short* qkv_bf = (unsigned short*)base;   base += (size_t)MPAD * 3 * DIM * 2;
    unsigned short* hid_bf = (unsigned short*)base;   base += (size_t)MPAD * MLP * 2;
    unsigned short* xp_bf  = (unsigned short*)base;   base += (size_t)BB * NP * PD * 2;
    // per-layer transposed bf16 weights
    unsigned short* wq_t = (unsigned short*)base;     base += (size_t)(3 * DIM) * DIM * 2;
    unsigned short* wo_t = (unsigned short*)base;     base += (size_t)DIM * DIM * 2;
    unsigned short* w1_t = (unsigned short*)base;     base += (size_t)MLP * DIM * 2;
    unsigned short* w2_t = (unsigned short*)base;     base += (size_t)DIM * MLP * 2;
    // 2-slice fp32 split-K partial buffer
    float* part = (float*)base;                       base += (size_t)2 * BS * DIM * 4;
    float* pe_f32 = (float*)hid_bf;   // patch-embed fp32 out, alias (consumed pre-loop)

    const int threads = 256;
    const int mblk = (BS + 127) / 128;   // 37

    patchify_k<<<(BB * NP * PD + 255) / 256, threads, 0, stream>>>(img, xp_bf);
    convT_k<<<dim3(DIM / 32, PD / 32), threads, 0, stream>>>(patch_w, wq_t, PD, DIM);
    mgemm_k<3, 1><<<dim3(DIM / 128, (BB * NP) / 128), threads, 0, stream>>>(
        xp_bf, wq_t, patch_b, pe_f32, BB * NP, DIM, PD);
    build_x_k<<<(BB * SS * DIM + 255) / 256, threads, 0, stream>>>(pe_f32, cls, pos, x);

    for (int l = 0; l < DEPTH; ++l) {
        // ln1: layer 0 plain; later layers fold in previous ff2 partials
        if (l == 0)
            ln_k<0><<<BS, threads, 0, stream>>>(x, nullptr, ln1_g, ln1_b, y_bf, nullptr);
        else
            ln_k<2><<<BS, threads, 0, stream>>>(x, part, ln1_g + l * DIM, ln1_b + l * DIM,
                                                y_bf, x);
        // all 4 weight conversions for this layer, one launch
        convT4_k<<<6912, threads, 0, stream>>>(
            qkv_w + (size_t)l * DIM * 3 * DIM,
            out_w + (size_t)l * DIM * DIM,
            ff1_w + (size_t)l * DIM * MLP,
            ff2_w + (size_t)l * MLP * DIM,
            wq_t, wo_t, w1_t, w2_t);
        mgemm_k<0, 1><<<dim3(3 * DIM / 128, mblk), threads, 0, stream>>>(
            y_bf, wq_t, nullptr, qkv_bf, BS, 3 * DIM, DIM);
        // MFMA flash attention -> t1
        mattn_k<<<dim3(BB * HEADS, NKT), threads, 0, stream>>>(qkv_bf, t1_bf);
        // attn-out: split-K x2 partial stores (no atomics); reduced inside ln2
        mgemm_k<4, 2><<<dim3(DIM / 128, mblk, 2), threads, 0, stream>>>(
            t1_bf, wo_t, out_b + l * DIM, part, BS, DIM, DIM);
        // ln2: x += attn partials, then LN
        ln_k<2><<<BS, threads, 0, stream>>>(x, part, ln2_g + l * DIM, ln2_b + l * DIM,
                                            y_bf, x);
        mgemm_k<1, 1><<<dim3(MLP / 128, mblk), threads, 0, stream>>>(
            y_bf, w1_t, ff1_b + l * MLP, hid_bf, BS, MLP, DIM);
        // ff2: split-K x2 partial stores; reduced inside next ln1 (or copy_out)
        mgemm_k<4, 2><<<dim3(DIM / 128, mblk, 2), threads, 0, stream>>>(
            hid_bf, w2_t, ff2_b + l * DIM, part, BS, DIM, MLP);
    }

    copy_out_k<2><<<(BB * NP * DIM + 255) / 256, threads, 0, stream>>>(x, part, out);
}